// Round 4
// baseline (2816.148 us; speedup 1.0000x reference)
//
#include <hip/hip_runtime.h>
#include <hip/hip_bf16.h>
#include <math.h>

typedef __attribute__((ext_vector_type(8))) short short8;
typedef __attribute__((ext_vector_type(4))) float f32x4;

#define MFMA16(a, b, c) __builtin_amdgcn_mfma_f32_16x16x32_bf16((a), (b), (c), 0, 0, 0)

#define BB 256
#define TT 64
#define VOCAB 10000
#define WORD 512
#define RNN 512
#define NC 2560          /* 2048 gates + 512 sentinel-gate pre */
#define NV 10001
#define NVP 10016
#define NTILES 626       /* NVP/16 */

__device__ __forceinline__ float sigf(float x) { return 1.f / (1.f + __expf(-x)); }
__device__ __forceinline__ float bf2f(short s) {
    union { unsigned int u; float f; } v;
    v.u = ((unsigned int)(unsigned short)s) << 16;
    return v.f;
}
__device__ __forceinline__ short f2bfs(float x) {
    __hip_bfloat16 h = __float2bfloat16(x);
    return *reinterpret_cast<short*>(&h);
}

// async global->LDS, 16B per lane. lds dest = wave-uniform base + lane*16 (HW rule).
__device__ __forceinline__ void gload_lds16(const void* g, void* l) {
    __builtin_amdgcn_global_load_lds((const __attribute__((address_space(1))) void*)g,
                                     (__attribute__((address_space(3))) void*)l, 16, 0, 0);
}

// stage one 16KB fragment-order tile: 4 waves x 4KB each
__device__ __forceinline__ void stage_tile(const short8* gsrc, void* lbuf, int w, int lane) {
    const char* g = (const char*)gsrc + w * 4096 + lane * 16;
    char* l = (char*)lbuf + w * 4096;
#pragma unroll
    for (int i = 0; i < 4; i++) gload_lds16(g + i * 1024, l + i * 1024);
}

// ---------------- prep kernels ----------------

// dst[n][k] = (float->bf16) src[k][n]; zero-fill for n in [N, dstN)
__global__ void transpose_cvt(const float* __restrict__ src, int K, int N, int ld,
                              __hip_bfloat16* __restrict__ dst, int dst_ld, int dstN) {
    __shared__ float tile[32][33];
    int k0 = blockIdx.y * 32, n0 = blockIdx.x * 32;
    int tx = threadIdx.x, ty = threadIdx.y;   // 32 x 8
#pragma unroll
    for (int i = 0; i < 32; i += 8) {
        int k = k0 + ty + i, n = n0 + tx;
        tile[ty + i][tx] = (k < K && n < N) ? src[(size_t)k * ld + n] : 0.f;
    }
    __syncthreads();
#pragma unroll
    for (int i = 0; i < 32; i += 8) {
        int n = n0 + ty + i, k = k0 + tx;
        if (n < dstN && k < K) dst[(size_t)n * dst_ld + k] = __float2bfloat16(tile[tx][ty + i]);
    }
}

// [ntiles*16][512] ([N][K]) -> fragment order: dst[ct][kt][lane] = src[(ct*16+(l&15))][kt*32+(l>>4)*8 ..+7]
__global__ void swizzle_frag(const short8* __restrict__ src, short8* __restrict__ dst, int ntiles) {
    int t = blockIdx.x * 256 + threadIdx.x;
    if (t >= ntiles * 1024) return;
    int ct = t >> 10, r = t & 1023, kt = r >> 6, l = r & 63;
    int li = l & 15, q = l >> 4;
    dst[t] = src[(size_t)(ct * 16 + li) * 64 + kt * 4 + q];
}

__global__ void zero_state(float* c, __hip_bfloat16* h) {
    int idx = blockIdx.x * 256 + threadIdx.x;   // 131072
    c[idx] = 0.f;
    h[idx] = __float2bfloat16(0.f);
}

__global__ void cvt_vis(const float* __restrict__ v, __hip_bfloat16* __restrict__ d) {
    int idx = blockIdx.x * 256 + threadIdx.x;   // 262144
    d[idx] = __float2bfloat16(v[idx]);
}

// visC[256][2560] = vis_bf16 @ visW + bias (b_lstm for n<2048 else vis2g_b)
__global__ __launch_bounds__(256) void gemm_vis(const __hip_bfloat16* __restrict__ A,
                                                const __hip_bfloat16* __restrict__ Bt,
                                                const float* __restrict__ b_lstm,
                                                const float* __restrict__ vis2g_b,
                                                float* __restrict__ C) {
    int wid = blockIdx.x * 4 + (threadIdx.x >> 6);   // 2560 waves: 16 x 160 tiles
    int mt = wid / 160, nt = wid % 160;
    int lane = threadIdx.x & 63, li = lane & 15, q = lane >> 4;
    const short8* Ap = (const short8*)A + (mt * 16 + li) * 128 + q;   // ld 1024 -> 128 chunks
    const short8* Bp = (const short8*)Bt + (nt * 16 + li) * 128 + q;
    f32x4 acc = {0.f, 0.f, 0.f, 0.f};
#pragma unroll
    for (int kk = 0; kk < 128; kk += 4) acc = MFMA16(Ap[kk], Bp[kk], acc);
    int col = nt * 16 + li;
    float bias = (col < 2048) ? b_lstm[col] : vis2g_b[col - 2048];
#pragma unroll
    for (int r = 0; r < 4; r++) {
        int row = mt * 16 + q * 4 + r;
        C[row * NC + col] = acc[r] + bias;
    }
}

// pre[t*256+b][2560] = emb[word(t,b)] @ WcatW + visC[b]   (bf16 out)
__global__ __launch_bounds__(256) void pre_gemm(const int* __restrict__ seqz,
                                                const float* __restrict__ emb,
                                                const short8* __restrict__ Bsw,   // 160 tiles, frag order
                                                const float* __restrict__ visC,
                                                __hip_bfloat16* __restrict__ pre) {
    __shared__ short8 lds[2][1024];
    int w = threadIdx.x >> 6, lane = threadIdx.x & 63, li = lane & 15, q = lane >> 4;
    int r0 = blockIdx.x * 128 + w * 32;

    short8 a0[16], a1[16];
    {
        int row = r0 + li;
        int t = row >> 8, b = row & 255;
        int wid_ = (t == 0) ? (VOCAB + 1) : seqz[b * TT + (t - 1)];
        const float* er = emb + (size_t)wid_ * WORD + q * 8;
#pragma unroll
        for (int kt = 0; kt < 16; kt++) {
            float4 f0 = ((const float4*)(er + kt * 32))[0];
            float4 f1 = ((const float4*)(er + kt * 32))[1];
            short8 v; v[0]=f2bfs(f0.x); v[1]=f2bfs(f0.y); v[2]=f2bfs(f0.z); v[3]=f2bfs(f0.w);
            v[4]=f2bfs(f1.x); v[5]=f2bfs(f1.y); v[6]=f2bfs(f1.z); v[7]=f2bfs(f1.w);
            a0[kt] = v;
        }
        row = r0 + 16 + li; t = row >> 8; b = row & 255;
        wid_ = (t == 0) ? (VOCAB + 1) : seqz[b * TT + (t - 1)];
        er = emb + (size_t)wid_ * WORD + q * 8;
#pragma unroll
        for (int kt = 0; kt < 16; kt++) {
            float4 f0 = ((const float4*)(er + kt * 32))[0];
            float4 f1 = ((const float4*)(er + kt * 32))[1];
            short8 v; v[0]=f2bfs(f0.x); v[1]=f2bfs(f0.y); v[2]=f2bfs(f0.z); v[3]=f2bfs(f0.w);
            v[4]=f2bfs(f1.x); v[5]=f2bfs(f1.y); v[6]=f2bfs(f1.z); v[7]=f2bfs(f1.w);
            a1[kt] = v;
        }
    }

    int t0 = blockIdx.y * 20, t1 = t0 + 20;   // 8 chunks x 20 = 160
    stage_tile(Bsw + (size_t)t0 * 1024, lds[0], w, lane);
    int ib = 0;
    for (int ct = t0; ct < t1; ++ct, ib ^= 1) {
        __syncthreads();
        if (ct + 1 < t1) stage_tile(Bsw + (size_t)(ct + 1) * 1024, lds[ib ^ 1], w, lane);
        const short8* B = lds[ib];
        f32x4 c0 = {0.f,0.f,0.f,0.f}, c1 = {0.f,0.f,0.f,0.f};
#pragma unroll
        for (int kt = 0; kt < 16; kt++) {
            short8 bv = B[kt * 64 + lane];
            c0 = MFMA16(a0[kt], bv, c0);
            c1 = MFMA16(a1[kt], bv, c1);
        }
        int col = ct * 16 + li;
#pragma unroll
        for (int r = 0; r < 4; r++) {
            int row0 = r0 + q * 4 + r, row1 = row0 + 16;
            pre[(size_t)row0 * NC + col] = __float2bfloat16(c0[r] + visC[(row0 & 255) * NC + col]);
            pre[(size_t)row1 * NC + col] = __float2bfloat16(c1[r] + visC[(row1 & 255) * NC + col]);
        }
    }
}

// ---------------- persistent recurrence v2: row-independent, weights in registers ----------------
// 256 blocks (16 rowgroups x 16 jgroups), 256 thr. Block owns rows [rg*16,+16), j-cols [jg*32,+32).
// Its 10 gate-tiles (5 gates x 2 j-tiles) of WcatH live in REGISTERS (4 waves: 2 teams x K-half,
// 5 tiles x 8 kt each = 160 VGPR). c lives in registers. Per step: load h (16KB), 40 MFMA/wave,
// LDS K-reduce, cell, store h/S, radix-16 barrier per rowgroup. Weights never refetched.
__global__ __launch_bounds__(256, 1) void steps_persist2(const short8* __restrict__ BHsw,
                                                         const __hip_bfloat16* __restrict__ pre,
                                                         __hip_bfloat16* __restrict__ h0,
                                                         __hip_bfloat16* __restrict__ h1,
                                                         __hip_bfloat16* __restrict__ S,
                                                         unsigned* __restrict__ bar) {
    __shared__ float red[2][5][256];
    int rg = blockIdx.x >> 4, jg = blockIdx.x & 15;
    int w = threadIdx.x >> 6, lane = threadIdx.x & 63, li = lane & 15, q = lane >> 4;
    int team = w >> 1, kh = w & 1;
    int jt = jg * 2 + team;                 // j-tile 0..31

    // load this wave's B fragments once (5 gates, its K-half)
    short8 Breg[5][8];
#pragma unroll
    for (int g = 0; g < 5; g++) {
        const short8* bp = BHsw + (size_t)(g * 32 + jt) * 1024 + (kh * 8) * 64 + lane;
#pragma unroll
        for (int kt = 0; kt < 8; kt++) Breg[g][kt] = bp[kt * 64];
    }

    float c0r = 0.f, c1r = 0.f, c2r = 0.f, c3r = 0.f;   // cell state, kh==0 waves only
    int jcol = jt * 16 + li;                             // this team's output col
    unsigned* cnt = bar + rg;

    for (int t = 0; t < TT; ++t) {
        const __hip_bfloat16* hc = (t & 1) ? h1 : h0;
        __hip_bfloat16* hn = (t & 1) ? h0 : h1;

        const short8* Ap = (const short8*)hc + (size_t)(rg * 16 + li) * 64 + kh * 32 + q;
        f32x4 a0 = {0.f,0.f,0.f,0.f}, a1 = a0, a2 = a0, a3 = a0, a4 = a0;
#pragma unroll
        for (int kt = 0; kt < 8; kt++) {
            short8 av = Ap[kt * 4];
            a0 = MFMA16(av, Breg[0][kt], a0);
            a1 = MFMA16(av, Breg[1][kt], a1);
            a2 = MFMA16(av, Breg[2][kt], a2);
            a3 = MFMA16(av, Breg[3][kt], a3);
            a4 = MFMA16(av, Breg[4][kt], a4);
        }
        if (kh == 1) {
#pragma unroll
            for (int r = 0; r < 4; r++) {
                red[team][0][lane * 4 + r] = a0[r];
                red[team][1][lane * 4 + r] = a1[r];
                red[team][2][lane * 4 + r] = a2[r];
                red[team][3][lane * 4 + r] = a3[r];
                red[team][4][lane * 4 + r] = a4[r];
            }
        }
        __syncthreads();
        if (kh == 0) {
#pragma unroll
            for (int r = 0; r < 4; r++) {
                int row = rg * 16 + q * 4 + r;
                const __hip_bfloat16* pv = pre + ((size_t)t * 256 + row) * NC;
                float ig = sigf(a0[r] + red[team][0][lane * 4 + r] + __bfloat162float(pv[jcol]));
                float fg = sigf(a1[r] + red[team][1][lane * 4 + r] + __bfloat162float(pv[512 + jcol]));
                float gg = tanhf(a2[r] + red[team][2][lane * 4 + r] + __bfloat162float(pv[1024 + jcol]));
                float og = sigf(a3[r] + red[team][3][lane * 4 + r] + __bfloat162float(pv[1536 + jcol]));
                float gp = sigf(a4[r] + red[team][4][lane * 4 + r] + __bfloat162float(pv[2048 + jcol]));
                float cold = (r == 0) ? c0r : (r == 1) ? c1r : (r == 2) ? c2r : c3r;
                float cn = fg * cold + ig * gg;
                if (r == 0) c0r = cn; else if (r == 1) c1r = cn; else if (r == 2) c2r = cn; else c3r = cn;
                float tc = tanhf(cn);
                int idx = row * 512 + jcol;
                hn[idx] = __float2bfloat16(og * tc);
                S[(size_t)t * 131072 + idx] = __float2bfloat16(gp * tc);
            }
        }
        if (t != TT - 1) {
            __syncthreads();   // stores complete (waitcnt) before fence/arrival
            if (threadIdx.x == 0) {
                __threadfence();
                atomicAdd(cnt, 1u);
                unsigned tgt = (unsigned)(t + 1) * 16u;
                while (__hip_atomic_load(cnt, __ATOMIC_RELAXED, __HIP_MEMORY_SCOPE_AGENT) < tgt)
                    __builtin_amdgcn_s_sleep(1);
            }
            __syncthreads();
            __threadfence();
        }
    }
}

// ---------------- fused output GEMM + sum-exp ----------------

__global__ __launch_bounds__(256) void lse_gemm(const short8* __restrict__ S8,
                                                const short8* __restrict__ Bsw,
                                                const float* __restrict__ ob,
                                                float* __restrict__ sumexp) {
    __shared__ short8 lds[2][1024];
    int w = threadIdx.x >> 6, lane = threadIdx.x & 63, li = lane & 15, q = lane >> 4;
    int r0 = blockIdx.x * 128 + w * 32;
    short8 a0[16], a1[16];
    const short8* Sp0 = S8 + (size_t)(r0 + li) * 64 + q;
    const short8* Sp1 = S8 + (size_t)(r0 + 16 + li) * 64 + q;
#pragma unroll
    for (int kt = 0; kt < 16; kt++) { a0[kt] = Sp0[kt * 4]; a1[kt] = Sp1[kt * 4]; }

    float s0[4] = {0.f,0.f,0.f,0.f}, s1[4] = {0.f,0.f,0.f,0.f};
    int t0 = blockIdx.y * 40;
    int t1 = t0 + 40 < NTILES ? t0 + 40 : NTILES;   // last chunk = 26

    stage_tile(Bsw + (size_t)t0 * 1024, lds[0], w, lane);
    int ib = 0;
    for (int ct = t0; ct < t1; ++ct, ib ^= 1) {
        __syncthreads();
        if (ct + 1 < t1) stage_tile(Bsw + (size_t)(ct + 1) * 1024, lds[ib ^ 1], w, lane);
        const short8* B = lds[ib];
        f32x4 c0 = {0.f,0.f,0.f,0.f}, c1 = {0.f,0.f,0.f,0.f};
#pragma unroll
        for (int kt = 0; kt < 16; kt++) {
            short8 bv = B[kt * 64 + lane];
            c0 = MFMA16(a0[kt], bv, c0);
            c1 = MFMA16(a1[kt], bv, c1);
        }
        int col = ct * 16 + li;
        if (col < NV) {
            float obv = ob[col];
#pragma unroll
            for (int r = 0; r < 4; r++) {
                s0[r] += __expf(c0[r] + obv);
                s1[r] += __expf(c1[r] + obv);
            }
        }
    }
#pragma unroll
    for (int off = 1; off < 16; off <<= 1) {
#pragma unroll
        for (int r = 0; r < 4; r++) { s0[r] += __shfl_xor(s0[r], off); s1[r] += __shfl_xor(s1[r], off); }
    }
    if (li == 0) {
#pragma unroll
        for (int r = 0; r < 4; r++) {
            atomicAdd(&sumexp[r0 + q * 4 + r], s0[r]);
            atomicAdd(&sumexp[r0 + 16 + q * 4 + r], s1[r]);
        }
    }
}

// out[row] = mask * (dot(S[row], out_W[:,tgt]) + ob[tgt] - log(sumexp[row]))
__global__ __launch_bounds__(256) void finalize_k(const __hip_bfloat16* __restrict__ S,
                                                  const __hip_bfloat16* __restrict__ Wt,
                                                  const float* __restrict__ ob,
                                                  const int* __restrict__ seqz,
                                                  const float* __restrict__ sumexp,
                                                  float* __restrict__ out) {
    int w = threadIdx.x >> 6, lane = threadIdx.x & 63;
    int row = blockIdx.x * 4 + w;        // 16384 rows, row = t*256 + b
    int t = row >> 8, b = row & 255;
    int tgt = seqz[b * TT + t];
    short8 sv = ((const short8*)(S + (size_t)row * 512))[lane];
    short8 wv = ((const short8*)(Wt + (size_t)tgt * 512))[lane];
    float d = 0.f;
#pragma unroll
    for (int i = 0; i < 8; i++) d += bf2f(sv[i]) * bf2f(wv[i]);
#pragma unroll
    for (int off = 1; off < 64; off <<= 1) d += __shfl_xor(d, off);
    if (lane == 0) {
        bool mk = (t == 0) || (seqz[b * TT + t - 1] != 0);
        out[row] = mk ? (d + ob[tgt] - logf(sumexp[row])) : 0.f;
    }
}

// ---------------- host ----------------

extern "C" void kernel_launch(void* const* d_in, const int* in_sizes, int n_in,
                              void* d_out, int out_size, void* d_ws, size_t ws_size,
                              hipStream_t stream) {
    const float* vis     = (const float*)d_in[0];
    const int*   seqz    = (const int*)d_in[1];
    const float* emb     = (const float*)d_in[2];
    const float* W_ih    = (const float*)d_in[3];
    const float* W_hh    = (const float*)d_in[4];
    const float* b_lstm  = (const float*)d_in[5];
    const float* vis2g_W = (const float*)d_in[6];
    const float* vis2g_b = (const float*)d_in[7];
    const float* w2g_W   = (const float*)d_in[8];
    const float* h2g_W   = (const float*)d_in[9];
    const float* out_W   = (const float*)d_in[10];
    const float* out_b   = (const float*)d_in[11];
    float* out = (float*)d_out;

    char* p = (char*)d_ws;
    auto carve = [&](size_t bytes) {
        void* r = (void*)p;
        p += (bytes + 255) & ~(size_t)255;
        return r;
    };
    __hip_bfloat16* WcatW = (__hip_bfloat16*)carve((size_t)NC * 512 * 2);       // [2560][512]
    __hip_bfloat16* WcatH = (__hip_bfloat16*)carve((size_t)NC * 512 * 2);       // [2560][512]
    __hip_bfloat16* visWt = (__hip_bfloat16*)carve((size_t)NC * 1024 * 2);      // [2560][1024]
    __hip_bfloat16* outWt = (__hip_bfloat16*)carve((size_t)NVP * 512 * 2);      // [10016][512]
    short8*         outSw = (short8*)carve((size_t)NTILES * 16384);             // frag order
    short8*         preBsw= (short8*)carve((size_t)160 * 16384);                // frag order
    short8*         WHsw  = (short8*)carve((size_t)160 * 16384);                // frag order
    __hip_bfloat16* visB  = (__hip_bfloat16*)carve((size_t)256 * 1024 * 2);
    float*          visC  = (float*)carve((size_t)256 * NC * 4);
    __hip_bfloat16* pre   = (__hip_bfloat16*)carve((size_t)TT * 256 * NC * 2);  // 84 MB
    float*          cbuf  = (float*)carve((size_t)256 * 512 * 4);
    __hip_bfloat16* hb0   = (__hip_bfloat16*)carve((size_t)256 * 512 * 2);
    __hip_bfloat16* hb1   = (__hip_bfloat16*)carve((size_t)256 * 512 * 2);
    __hip_bfloat16* S     = (__hip_bfloat16*)carve((size_t)TT * 256 * 512 * 2);
    float*          sume  = (float*)carve((size_t)TT * 256 * 4);
    unsigned*       bar   = (unsigned*)carve(256);

    dim3 tb(32, 8);
    // WcatW: word -> [gates | w2g];  WcatH: h -> [gates | h2g]   (both [2560][512] = [N][K])
    transpose_cvt<<<dim3(64, 16), tb, 0, stream>>>(W_ih + 1024 * 2048, 512, 2048, 2048, WcatW, 512, 2048);
    transpose_cvt<<<dim3(16, 16), tb, 0, stream>>>(w2g_W, 512, 512, 512, WcatW + 2048 * 512, 512, 512);
    transpose_cvt<<<dim3(64, 16), tb, 0, stream>>>(W_hh, 512, 2048, 2048, WcatH, 512, 2048);
    transpose_cvt<<<dim3(16, 16), tb, 0, stream>>>(h2g_W, 512, 512, 512, WcatH + 2048 * 512, 512, 512);
    // visWt: vis -> [gates | vis2g]  [2560][1024]
    transpose_cvt<<<dim3(64, 32), tb, 0, stream>>>(W_ih, 1024, 2048, 2048, visWt, 1024, 2048);
    transpose_cvt<<<dim3(16, 32), tb, 0, stream>>>(vis2g_W, 1024, 512, 512, visWt + 2048 * 1024, 1024, 512);
    // out_W transposed, zero-padded to 10016 rows
    transpose_cvt<<<dim3(313, 16), tb, 0, stream>>>(out_W, 512, NV, NV, outWt, 512, NVP);
    // fragment-order swizzles
    swizzle_frag<<<2504, 256, 0, stream>>>((const short8*)outWt, outSw, NTILES);
    swizzle_frag<<<640, 256, 0, stream>>>((const short8*)WcatW, preBsw, 160);
    swizzle_frag<<<640, 256, 0, stream>>>((const short8*)WcatH, WHsw, 160);

    zero_state<<<512, 256, 0, stream>>>(cbuf, hb0);
    cvt_vis<<<1024, 256, 0, stream>>>(vis, visB);
    gemm_vis<<<640, 256, 0, stream>>>(visB, visWt, b_lstm, vis2g_b, visC);
    pre_gemm<<<dim3(128, 8), 256, 0, stream>>>(seqz, emb, preBsw, visC, pre);

    hipMemsetAsync(sume, 0, (size_t)TT * 256 * 4 + 256, stream);   // sume + bar (contiguous)

    steps_persist2<<<256, 256, 0, stream>>>(WHsw, pre, hb0, hb1, S, bar);

    lse_gemm<<<dim3(128, 16), 256, 0, stream>>>((const short8*)S, outSw, out_b, sume);
    finalize_k<<<4096, 256, 0, stream>>>(S, outWt, out_b, seqz, sume, out);
}

// Round 5
// 1068.119 us; speedup vs baseline: 2.6365x; 2.6365x over previous
//
#include <hip/hip_runtime.h>
#include <hip/hip_bf16.h>
#include <math.h>

typedef __attribute__((ext_vector_type(8))) short short8;
typedef __attribute__((ext_vector_type(4))) float f32x4;

#define MFMA16(a, b, c) __builtin_amdgcn_mfma_f32_16x16x32_bf16((a), (b), (c), 0, 0, 0)

#define BB 256
#define TT 64
#define VOCAB 10000
#define WORD 512
#define RNN 512
#define NC 2560          /* 2048 gates + 512 sentinel-gate pre */
#define NV 10001
#define NVP 10016
#define NTILES 626       /* NVP/16 */

__device__ __forceinline__ float sigf(float x) { return 1.f / (1.f + __expf(-x)); }
__device__ __forceinline__ float bf2f(short s) {
    union { unsigned int u; float f; } v;
    v.u = ((unsigned int)(unsigned short)s) << 16;
    return v.f;
}
__device__ __forceinline__ short f2bfs(float x) {
    __hip_bfloat16 h = __float2bfloat16(x);
    return *reinterpret_cast<short*>(&h);
}

// async global->LDS, 16B per lane. lds dest = wave-uniform base + lane*16 (HW rule).
__device__ __forceinline__ void gload_lds16(const void* g, void* l) {
    __builtin_amdgcn_global_load_lds((const __attribute__((address_space(1))) void*)g,
                                     (__attribute__((address_space(3))) void*)l, 16, 0, 0);
}

// stage one 16KB fragment-order tile: 4 waves x 4KB each
__device__ __forceinline__ void stage_tile(const short8* gsrc, void* lbuf, int w, int lane) {
    const char* g = (const char*)gsrc + w * 4096 + lane * 16;
    char* l = (char*)lbuf + w * 4096;
#pragma unroll
    for (int i = 0; i < 4; i++) gload_lds16(g + i * 1024, l + i * 1024);
}

// ---------------- prep kernels ----------------

// dst[n][k] = (float->bf16) src[k][n]; zero-fill for n in [N, dstN)
__global__ void transpose_cvt(const float* __restrict__ src, int K, int N, int ld,
                              __hip_bfloat16* __restrict__ dst, int dst_ld, int dstN) {
    __shared__ float tile[32][33];
    int k0 = blockIdx.y * 32, n0 = blockIdx.x * 32;
    int tx = threadIdx.x, ty = threadIdx.y;   // 32 x 8
#pragma unroll
    for (int i = 0; i < 32; i += 8) {
        int k = k0 + ty + i, n = n0 + tx;
        tile[ty + i][tx] = (k < K && n < N) ? src[(size_t)k * ld + n] : 0.f;
    }
    __syncthreads();
#pragma unroll
    for (int i = 0; i < 32; i += 8) {
        int n = n0 + ty + i, k = k0 + tx;
        if (n < dstN && k < K) dst[(size_t)n * dst_ld + k] = __float2bfloat16(tile[tx][ty + i]);
    }
}

// [ntiles*16][512] ([N][K]) -> fragment order: dst[ct][kt][lane] = src[(ct*16+(l&15))][kt*32+(l>>4)*8 ..+7]
__global__ void swizzle_frag(const short8* __restrict__ src, short8* __restrict__ dst, int ntiles) {
    int t = blockIdx.x * 256 + threadIdx.x;
    if (t >= ntiles * 1024) return;
    int ct = t >> 10, r = t & 1023, kt = r >> 6, l = r & 63;
    int li = l & 15, q = l >> 4;
    dst[t] = src[(size_t)(ct * 16 + li) * 64 + kt * 4 + q];
}

__global__ void zero_state(float* c, __hip_bfloat16* h) {
    int idx = blockIdx.x * 256 + threadIdx.x;   // 131072
    c[idx] = 0.f;
    h[idx] = __float2bfloat16(0.f);
}

__global__ void cvt_vis(const float* __restrict__ v, __hip_bfloat16* __restrict__ d) {
    int idx = blockIdx.x * 256 + threadIdx.x;   // 262144
    d[idx] = __float2bfloat16(v[idx]);
}

// visC[256][2560] = vis_bf16 @ visW + bias (b_lstm for n<2048 else vis2g_b)
__global__ __launch_bounds__(256) void gemm_vis(const __hip_bfloat16* __restrict__ A,
                                                const __hip_bfloat16* __restrict__ Bt,
                                                const float* __restrict__ b_lstm,
                                                const float* __restrict__ vis2g_b,
                                                float* __restrict__ C) {
    int wid = blockIdx.x * 4 + (threadIdx.x >> 6);   // 2560 waves: 16 x 160 tiles
    int mt = wid / 160, nt = wid % 160;
    int lane = threadIdx.x & 63, li = lane & 15, q = lane >> 4;
    const short8* Ap = (const short8*)A + (mt * 16 + li) * 128 + q;   // ld 1024 -> 128 chunks
    const short8* Bp = (const short8*)Bt + (nt * 16 + li) * 128 + q;
    f32x4 acc = {0.f, 0.f, 0.f, 0.f};
#pragma unroll
    for (int kk = 0; kk < 128; kk += 4) acc = MFMA16(Ap[kk], Bp[kk], acc);
    int col = nt * 16 + li;
    float bias = (col < 2048) ? b_lstm[col] : vis2g_b[col - 2048];
#pragma unroll
    for (int r = 0; r < 4; r++) {
        int row = mt * 16 + q * 4 + r;
        C[row * NC + col] = acc[r] + bias;
    }
}

// pre[t*256+b][2560] = emb[word(t,b)] @ WcatW + visC[b]   (bf16 out)
__global__ __launch_bounds__(256) void pre_gemm(const int* __restrict__ seqz,
                                                const float* __restrict__ emb,
                                                const short8* __restrict__ Bsw,   // 160 tiles, frag order
                                                const float* __restrict__ visC,
                                                __hip_bfloat16* __restrict__ pre) {
    __shared__ short8 lds[2][1024];
    int w = threadIdx.x >> 6, lane = threadIdx.x & 63, li = lane & 15, q = lane >> 4;
    int r0 = blockIdx.x * 128 + w * 32;

    short8 a0[16], a1[16];
    {
        int row = r0 + li;
        int t = row >> 8, b = row & 255;
        int wid_ = (t == 0) ? (VOCAB + 1) : seqz[b * TT + (t - 1)];
        const float* er = emb + (size_t)wid_ * WORD + q * 8;
#pragma unroll
        for (int kt = 0; kt < 16; kt++) {
            float4 f0 = ((const float4*)(er + kt * 32))[0];
            float4 f1 = ((const float4*)(er + kt * 32))[1];
            short8 v; v[0]=f2bfs(f0.x); v[1]=f2bfs(f0.y); v[2]=f2bfs(f0.z); v[3]=f2bfs(f0.w);
            v[4]=f2bfs(f1.x); v[5]=f2bfs(f1.y); v[6]=f2bfs(f1.z); v[7]=f2bfs(f1.w);
            a0[kt] = v;
        }
        row = r0 + 16 + li; t = row >> 8; b = row & 255;
        wid_ = (t == 0) ? (VOCAB + 1) : seqz[b * TT + (t - 1)];
        er = emb + (size_t)wid_ * WORD + q * 8;
#pragma unroll
        for (int kt = 0; kt < 16; kt++) {
            float4 f0 = ((const float4*)(er + kt * 32))[0];
            float4 f1 = ((const float4*)(er + kt * 32))[1];
            short8 v; v[0]=f2bfs(f0.x); v[1]=f2bfs(f0.y); v[2]=f2bfs(f0.z); v[3]=f2bfs(f0.w);
            v[4]=f2bfs(f1.x); v[5]=f2bfs(f1.y); v[6]=f2bfs(f1.z); v[7]=f2bfs(f1.w);
            a1[kt] = v;
        }
    }

    int t0 = blockIdx.y * 20, t1 = t0 + 20;   // 8 chunks x 20 = 160
    stage_tile(Bsw + (size_t)t0 * 1024, lds[0], w, lane);
    int ib = 0;
    for (int ct = t0; ct < t1; ++ct, ib ^= 1) {
        __syncthreads();
        if (ct + 1 < t1) stage_tile(Bsw + (size_t)(ct + 1) * 1024, lds[ib ^ 1], w, lane);
        const short8* B = lds[ib];
        f32x4 c0 = {0.f,0.f,0.f,0.f}, c1 = {0.f,0.f,0.f,0.f};
#pragma unroll
        for (int kt = 0; kt < 16; kt++) {
            short8 bv = B[kt * 64 + lane];
            c0 = MFMA16(a0[kt], bv, c0);
            c1 = MFMA16(a1[kt], bv, c1);
        }
        int col = ct * 16 + li;
#pragma unroll
        for (int r = 0; r < 4; r++) {
            int row0 = r0 + q * 4 + r, row1 = row0 + 16;
            pre[(size_t)row0 * NC + col] = __float2bfloat16(c0[r] + visC[(row0 & 255) * NC + col]);
            pre[(size_t)row1 * NC + col] = __float2bfloat16(c1[r] + visC[(row1 & 255) * NC + col]);
        }
    }
}

// ---------------- per-step kernel: G = h @ WcatH + pre[t] -> cell ----------------
// One wave per (16-row x 16-col) tile: 512 blocks x 64 thr (16 mt x 32 jt).
// B in fragment order (L2-resident), 5 independent MFMA chains, no LDS, no fences.
__global__ __launch_bounds__(64) void step_h(const short8* __restrict__ BHsw,
                                             const __hip_bfloat16* __restrict__ pre_t,
                                             float* __restrict__ c,
                                             const __hip_bfloat16* __restrict__ hc,
                                             __hip_bfloat16* __restrict__ hn,
                                             __hip_bfloat16* __restrict__ St) {
    int wid = blockIdx.x;                // 0..511 : 16 mt x 32 jt
    int mt = wid >> 5, jt = wid & 31;
    int lane = threadIdx.x & 63, li = lane & 15, q = lane >> 4;

    const short8* Ap = (const short8*)hc + (size_t)(mt * 16 + li) * 64 + q;
    const short8* B0 = BHsw + (size_t)(0 * 32 + jt) * 1024 + lane;
    const short8* B1 = BHsw + (size_t)(1 * 32 + jt) * 1024 + lane;
    const short8* B2 = BHsw + (size_t)(2 * 32 + jt) * 1024 + lane;
    const short8* B3 = BHsw + (size_t)(3 * 32 + jt) * 1024 + lane;
    const short8* B4 = BHsw + (size_t)(4 * 32 + jt) * 1024 + lane;

    f32x4 g0 = {0.f,0.f,0.f,0.f}, g1 = g0, g2 = g0, g3 = g0, g4 = g0;
#pragma unroll
    for (int kt = 0; kt < 16; kt++) {
        short8 av = Ap[kt * 4];
        g0 = MFMA16(av, B0[kt * 64], g0);
        g1 = MFMA16(av, B1[kt * 64], g1);
        g2 = MFMA16(av, B2[kt * 64], g2);
        g3 = MFMA16(av, B3[kt * 64], g3);
        g4 = MFMA16(av, B4[kt * 64], g4);
    }

    int jcol = jt * 16 + li;
#pragma unroll
    for (int r = 0; r < 4; r++) {
        int row = mt * 16 + q * 4 + r;
        const __hip_bfloat16* pv = pre_t + (size_t)row * NC;
        float ig = sigf(g0[r] + __bfloat162float(pv[jcol]));
        float fg = sigf(g1[r] + __bfloat162float(pv[512 + jcol]));
        float gg = tanhf(g2[r] + __bfloat162float(pv[1024 + jcol]));
        float og = sigf(g3[r] + __bfloat162float(pv[1536 + jcol]));
        float gp = sigf(g4[r] + __bfloat162float(pv[2048 + jcol]));
        int idx = row * 512 + jcol;
        float cn = fg * c[idx] + ig * gg;
        float tc = tanhf(cn);
        c[idx] = cn;
        hn[idx] = __float2bfloat16(og * tc);
        St[idx] = __float2bfloat16(gp * tc);
    }
}

// ---------------- fused output GEMM + sum-exp ----------------

__global__ __launch_bounds__(256) void lse_gemm(const short8* __restrict__ S8,
                                                const short8* __restrict__ Bsw,
                                                const float* __restrict__ ob,
                                                float* __restrict__ sumexp) {
    __shared__ short8 lds[2][1024];
    int w = threadIdx.x >> 6, lane = threadIdx.x & 63, li = lane & 15, q = lane >> 4;
    int r0 = blockIdx.x * 128 + w * 32;
    short8 a0[16], a1[16];
    const short8* Sp0 = S8 + (size_t)(r0 + li) * 64 + q;
    const short8* Sp1 = S8 + (size_t)(r0 + 16 + li) * 64 + q;
#pragma unroll
    for (int kt = 0; kt < 16; kt++) { a0[kt] = Sp0[kt * 4]; a1[kt] = Sp1[kt * 4]; }

    float s0[4] = {0.f,0.f,0.f,0.f}, s1[4] = {0.f,0.f,0.f,0.f};
    int t0 = blockIdx.y * 40;
    int t1 = t0 + 40 < NTILES ? t0 + 40 : NTILES;   // last chunk = 26

    stage_tile(Bsw + (size_t)t0 * 1024, lds[0], w, lane);
    int ib = 0;
    for (int ct = t0; ct < t1; ++ct, ib ^= 1) {
        __syncthreads();
        if (ct + 1 < t1) stage_tile(Bsw + (size_t)(ct + 1) * 1024, lds[ib ^ 1], w, lane);
        const short8* B = lds[ib];
        f32x4 c0 = {0.f,0.f,0.f,0.f}, c1 = {0.f,0.f,0.f,0.f};
#pragma unroll
        for (int kt = 0; kt < 16; kt++) {
            short8 bv = B[kt * 64 + lane];
            c0 = MFMA16(a0[kt], bv, c0);
            c1 = MFMA16(a1[kt], bv, c1);
        }
        int col = ct * 16 + li;
        if (col < NV) {
            float obv = ob[col];
#pragma unroll
            for (int r = 0; r < 4; r++) {
                s0[r] += __expf(c0[r] + obv);
                s1[r] += __expf(c1[r] + obv);
            }
        }
    }
#pragma unroll
    for (int off = 1; off < 16; off <<= 1) {
#pragma unroll
        for (int r = 0; r < 4; r++) { s0[r] += __shfl_xor(s0[r], off); s1[r] += __shfl_xor(s1[r], off); }
    }
    if (li == 0) {
#pragma unroll
        for (int r = 0; r < 4; r++) {
            atomicAdd(&sumexp[r0 + q * 4 + r], s0[r]);
            atomicAdd(&sumexp[r0 + 16 + q * 4 + r], s1[r]);
        }
    }
}

// out[row] = mask * (dot(S[row], out_W[:,tgt]) + ob[tgt] - log(sumexp[row]))
__global__ __launch_bounds__(256) void finalize_k(const __hip_bfloat16* __restrict__ S,
                                                  const __hip_bfloat16* __restrict__ Wt,
                                                  const float* __restrict__ ob,
                                                  const int* __restrict__ seqz,
                                                  const float* __restrict__ sumexp,
                                                  float* __restrict__ out) {
    int w = threadIdx.x >> 6, lane = threadIdx.x & 63;
    int row = blockIdx.x * 4 + w;        // 16384 rows, row = t*256 + b
    int t = row >> 8, b = row & 255;
    int tgt = seqz[b * TT + t];
    short8 sv = ((const short8*)(S + (size_t)row * 512))[lane];
    short8 wv = ((const short8*)(Wt + (size_t)tgt * 512))[lane];
    float d = 0.f;
#pragma unroll
    for (int i = 0; i < 8; i++) d += bf2f(sv[i]) * bf2f(wv[i]);
#pragma unroll
    for (int off = 1; off < 64; off <<= 1) d += __shfl_xor(d, off);
    if (lane == 0) {
        bool mk = (t == 0) || (seqz[b * TT + t - 1] != 0);
        out[row] = mk ? (d + ob[tgt] - logf(sumexp[row])) : 0.f;
    }
}

// ---------------- host ----------------

extern "C" void kernel_launch(void* const* d_in, const int* in_sizes, int n_in,
                              void* d_out, int out_size, void* d_ws, size_t ws_size,
                              hipStream_t stream) {
    const float* vis     = (const float*)d_in[0];
    const int*   seqz    = (const int*)d_in[1];
    const float* emb     = (const float*)d_in[2];
    const float* W_ih    = (const float*)d_in[3];
    const float* W_hh    = (const float*)d_in[4];
    const float* b_lstm  = (const float*)d_in[5];
    const float* vis2g_W = (const float*)d_in[6];
    const float* vis2g_b = (const float*)d_in[7];
    const float* w2g_W   = (const float*)d_in[8];
    const float* h2g_W   = (const float*)d_in[9];
    const float* out_W   = (const float*)d_in[10];
    const float* out_b   = (const float*)d_in[11];
    float* out = (float*)d_out;

    char* p = (char*)d_ws;
    auto carve = [&](size_t bytes) {
        void* r = (void*)p;
        p += (bytes + 255) & ~(size_t)255;
        return r;
    };
    __hip_bfloat16* WcatW = (__hip_bfloat16*)carve((size_t)NC * 512 * 2);       // [2560][512]
    __hip_bfloat16* WcatH = (__hip_bfloat16*)carve((size_t)NC * 512 * 2);       // [2560][512]
    __hip_bfloat16* visWt = (__hip_bfloat16*)carve((size_t)NC * 1024 * 2);      // [2560][1024]
    __hip_bfloat16* outWt = (__hip_bfloat16*)carve((size_t)NVP * 512 * 2);      // [10016][512]
    short8*         outSw = (short8*)carve((size_t)NTILES * 16384);             // frag order
    short8*         preBsw= (short8*)carve((size_t)160 * 16384);                // frag order
    short8*         WHsw  = (short8*)carve((size_t)160 * 16384);                // frag order
    __hip_bfloat16* visB  = (__hip_bfloat16*)carve((size_t)256 * 1024 * 2);
    float*          visC  = (float*)carve((size_t)256 * NC * 4);
    __hip_bfloat16* pre   = (__hip_bfloat16*)carve((size_t)TT * 256 * NC * 2);  // 84 MB
    float*          cbuf  = (float*)carve((size_t)256 * 512 * 4);
    __hip_bfloat16* hb0   = (__hip_bfloat16*)carve((size_t)256 * 512 * 2);
    __hip_bfloat16* hb1   = (__hip_bfloat16*)carve((size_t)256 * 512 * 2);
    __hip_bfloat16* S     = (__hip_bfloat16*)carve((size_t)TT * 256 * 512 * 2);
    float*          sume  = (float*)carve((size_t)TT * 256 * 4);

    dim3 tb(32, 8);
    // WcatW: word -> [gates | w2g];  WcatH: h -> [gates | h2g]   (both [2560][512] = [N][K])
    transpose_cvt<<<dim3(64, 16), tb, 0, stream>>>(W_ih + 1024 * 2048, 512, 2048, 2048, WcatW, 512, 2048);
    transpose_cvt<<<dim3(16, 16), tb, 0, stream>>>(w2g_W, 512, 512, 512, WcatW + 2048 * 512, 512, 512);
    transpose_cvt<<<dim3(64, 16), tb, 0, stream>>>(W_hh, 512, 2048, 2048, WcatH, 512, 2048);
    transpose_cvt<<<dim3(16, 16), tb, 0, stream>>>(h2g_W, 512, 512, 512, WcatH + 2048 * 512, 512, 512);
    // visWt: vis -> [gates | vis2g]  [2560][1024]
    transpose_cvt<<<dim3(64, 32), tb, 0, stream>>>(W_ih, 1024, 2048, 2048, visWt, 1024, 2048);
    transpose_cvt<<<dim3(16, 32), tb, 0, stream>>>(vis2g_W, 1024, 512, 512, visWt + 2048 * 1024, 1024, 512);
    // out_W transposed, zero-padded to 10016 rows
    transpose_cvt<<<dim3(313, 16), tb, 0, stream>>>(out_W, 512, NV, NV, outWt, 512, NVP);
    // fragment-order swizzles
    swizzle_frag<<<2504, 256, 0, stream>>>((const short8*)outWt, outSw, NTILES);
    swizzle_frag<<<640, 256, 0, stream>>>((const short8*)WcatW, preBsw, 160);
    swizzle_frag<<<640, 256, 0, stream>>>((const short8*)WcatH, WHsw, 160);

    zero_state<<<512, 256, 0, stream>>>(cbuf, hb0);
    cvt_vis<<<1024, 256, 0, stream>>>(vis, visB);
    gemm_vis<<<640, 256, 0, stream>>>(visB, visWt, b_lstm, vis2g_b, visC);
    pre_gemm<<<dim3(128, 8), 256, 0, stream>>>(seqz, emb, preBsw, visC, pre);

    hipMemsetAsync(sume, 0, (size_t)TT * 256 * 4, stream);

    __hip_bfloat16* hcur = hb0;
    __hip_bfloat16* hnxt = hb1;
    for (int t = 0; t < TT; ++t) {
        step_h<<<512, 64, 0, stream>>>(WHsw, pre + (size_t)t * 256 * NC, cbuf,
                                       hcur, hnxt, S + (size_t)t * 131072);
        __hip_bfloat16* tmp = hcur; hcur = hnxt; hnxt = tmp;
    }

    lse_gemm<<<dim3(128, 16), 256, 0, stream>>>((const short8*)S, outSw, out_b, sume);
    finalize_k<<<4096, 256, 0, stream>>>(S, outWt, out_b, seqz, sume, out);
}